// Round 15
// baseline (878.826 us; speedup 1.0000x reference)
//
#include <hip/hip_runtime.h>

#define N_V   11965
#define N_HE  189
#define NPAIR 35895
#define BB    256
#define SS    400
#define DD    128
#define BSR   102400   // B*S rows
#define NVD   (N_V * DD)

typedef __bf16 bf16x8 __attribute__((ext_vector_type(8)));
typedef float  f32x4  __attribute__((ext_vector_type(4)));
typedef float  f32x2  __attribute__((ext_vector_type(2)));

__device__ __forceinline__ ushort f2bf(float f) {
    unsigned x = __float_as_uint(f);
    return (ushort)((x + 0x7FFFu + ((x >> 16) & 1u)) >> 16);
}
__device__ __forceinline__ float bf2f(ushort u) { return __uint_as_float(((unsigned)u) << 16); }
__device__ __forceinline__ float sigm(float x) { return 1.f / (1.f + __expf(-x)); }
__device__ __forceinline__ float tanh_f(float x) { return 2.f * sigm(2.f * x) - 1.f; }
__device__ __forceinline__ float blo(unsigned u) { return __uint_as_float(u << 16); }
__device__ __forceinline__ float bhi(unsigned u) { return __uint_as_float(u); }

// ---------------------------------------------------------------------------
// P1: fused prep — BN fold, e_deg count, transposes (W1/Wg/Ug->bf16),
// W2''=W2*diag(s2)*WiE fold, t2'=t2@WiE, e_table cvt, per-table folds, sdots.
// ---------------------------------------------------------------------------
struct P1Args {
    const int* pair_e;
    const float *b1, *g1, *be1, *m1, *v1;
    const float *b2, *g2, *be2, *m2, *v2;
    const float *W1, *W2, *Wi, *Wg, *Ug, *e_t;
    const float *ed_t, *ep_t, *c_t, *cd_t, *a_t, *bi, *bg;
    const float *ha_t, *ca_t, *as_t, *it_t, *Ws;
    int* e_deg;
    float* aff;
    ushort *W1T, *W2ppT, *WgT, *UgT, *e_tb;
    float *t2p, *edW, *epW, *cW, *cdW, *agi, *sd;
};

__global__ __launch_bounds__(384) void p1_kernel(P1Args A) {
    int bid = blockIdx.x, t = threadIdx.x;
    if (bid == 0) {  // BN1 affine fold
        if (t < 128) {
            float s = A.g1[t] * rsqrtf(A.v1[t] + 1e-5f);
            A.aff[t] = s;
            A.aff[128 + t] = A.b1[t] * s + A.be1[t] - A.m1[t] * s;
        }
        return;
    }
    bid -= 1;
    if (bid < 94) {  // e_deg count
        int p = bid * 384 + t;
        if (p < NPAIR) atomicAdd(&A.e_deg[A.pair_e[p]], 1);
        return;
    }
    bid -= 94;
    if (bid < 43) {  // W1T
        int i = bid * 384 + t;
        if (i < 16384) { int k = i >> 7, n = i & 127; A.W1T[n * 128 + k] = f2bf(A.W1[i]); }
        return;
    }
    bid -= 43;
    if (bid < 128) {  // W2ppT[n][k] = bf16( sum_j W2[k][j]*s2[j]*Wi[j][n] )
        int k = bid;
        if (t < 128) {
            float acc = 0.f;
            for (int j = 0; j < 128; ++j) {
                float s2 = A.g2[j] * rsqrtf(A.v2[j] + 1e-5f);
                acc += A.W2[k * 128 + j] * s2 * A.Wi[j * 128 + t];
            }
            A.W2ppT[t * 128 + k] = f2bf(acc);
        }
        return;
    }
    bid -= 128;
    if (bid < 1) {  // t2p
        if (t < 128) {
            float acc = 0.f;
            for (int j = 0; j < 128; ++j) {
                float s2 = A.g2[j] * rsqrtf(A.v2[j] + 1e-5f);
                float t2 = A.b2[j] * s2 + A.be2[j] - A.m2[j] * s2;
                acc += t2 * A.Wi[j * 128 + t];
            }
            A.t2p[t] = acc;
        }
        return;
    }
    bid -= 1;
    if (bid < 128) {  // WgT
        int i = bid * 384 + t;
        if (i < 49152) { int k = i / 384, n = i % 384; A.WgT[n * 128 + k] = f2bf(A.Wg[i]); }
        return;
    }
    bid -= 128;
    if (bid < 128) {  // UgT
        int i = bid * 384 + t;
        if (i < 49152) { int k = i / 384, n = i % 384; A.UgT[n * 128 + k] = f2bf(A.Ug[i]); }
        return;
    }
    bid -= 128;
    if (bid < 998) {  // e_table cvt x4
        int i4 = bid * 1536 + t * 4;
        if (i4 < NVD) {
            float4 v = *(const float4*)(A.e_t + i4);
            ushort4 o;
            o.x = f2bf(v.x); o.y = f2bf(v.y); o.z = f2bf(v.z); o.w = f2bf(v.w);
            *(ushort4*)(A.e_tb + i4) = o;
        }
        return;
    }
    bid -= 998;
    if (bid < 101) {  // edW
        if (t < 128) {
            float acc = 0.f;
            for (int k = 0; k < 128; ++k)
                acc += A.ed_t[bid * 128 + k] * A.Wi[(128 + k) * 128 + t];
            A.edW[bid * 128 + t] = acc + A.bi[t];
        }
        return;
    }
    bid -= 101;
    if (bid < 101) {  // epW
        if (t < 128) {
            float acc = 0.f;
            for (int k = 0; k < 128; ++k)
                acc += A.ep_t[bid * 128 + k] * A.Wi[(256 + k) * 128 + t];
            A.epW[bid * 128 + t] = acc;
        }
        return;
    }
    bid -= 101;
    if (bid < 189) {  // cW
        if (t < 128) {
            float acc = 0.f;
            for (int k = 0; k < 128; ++k)
                acc += A.c_t[bid * 128 + k] * A.Wi[(384 + k) * 128 + t];
            A.cW[bid * 128 + t] = acc;
        }
        return;
    }
    bid -= 189;
    if (bid < 101) {  // cdW
        if (t < 128) {
            float acc = 0.f;
            for (int k = 0; k < 128; ++k)
                acc += A.cd_t[bid * 128 + k] * A.Wi[(512 + k) * 128 + t];
            A.cdW[bid * 128 + t] = acc;
        }
        return;
    }
    bid -= 101;
    if (bid < 2) {  // a_gi
        float acc = 0.f;
        for (int k = 0; k < 128; ++k)
            acc += A.a_t[bid * 128 + k] * A.Wg[(128 + k) * 384 + t];
        A.agi[bid * 384 + t] = acc + A.bg[t];
        return;
    }
    bid -= 2;
    {  // sdots (38 blocks)
        int r = bid;
        const float* tab; int woff, row;
        if (r < 11)      { tab = A.ha_t; row = r;      woff = 0;   }
        else if (r < 22) { tab = A.ca_t; row = r - 11; woff = 128; }
        else if (r < 30) { tab = A.as_t; row = r - 22; woff = 256; }
        else             { tab = A.it_t; row = r - 30; woff = 384; }
        if (t < 64) {
            float p = tab[row * 128 + t] * A.Ws[woff + t]
                    + tab[row * 128 + 64 + t] * A.Ws[woff + 64 + t];
            #pragma unroll
            for (int o = 32; o > 0; o >>= 1) p += __shfl_xor(p, o);
            if (t == 0) A.sd[r] = p;
        }
    }
}

// ---------------------------------------------------------------------------
// CSR build (fused prefix+fill)
// ---------------------------------------------------------------------------
__global__ __launch_bounds__(384) void csr_build(
    const int* __restrict__ e_deg, const int* __restrict__ pair_e,
    const int* __restrict__ pair_v, int* __restrict__ start,
    int* __restrict__ cursor, int* __restrict__ list) {
    __shared__ int sc[256];
    __shared__ int sx[256];
    int t = threadIdx.x;
    int d = 0;
    if (t < 256) { d = (t < N_HE) ? e_deg[t] : 0; sc[t] = d; }
    __syncthreads();
    for (int off = 1; off < 256; off <<= 1) {
        int v = (t < 256 && t >= off) ? sc[t - off] : 0;
        __syncthreads();
        if (t < 256) sc[t] += v;
        __syncthreads();
    }
    if (t < 256) sx[t] = sc[t] - d;
    __syncthreads();
    if (blockIdx.x == 0) {
        if (t < N_HE) start[t] = sx[t];
        if (t == 0) start[N_HE] = sc[N_HE - 1];
    }
    int p = blockIdx.x * 384 + t;
    if (p < NPAIR) {
        int e = pair_e[p];
        int pos = atomicAdd(&cursor[e], 1);
        list[sx[e] + pos] = pair_v[p];
    }
}

// ---------------------------------------------------------------------------
// conv1 GEMM (N=128): Y = BN1(e_tb @ W1)
// ---------------------------------------------------------------------------
__global__ __launch_bounds__(256) void gemm_mfma8(
    const ushort* __restrict__ Amat, const ushort* __restrict__ BT,
    float* __restrict__ out, int M,
    const float* __restrict__ colS, const float* __restrict__ colB) {
    int lane = threadIdx.x & 63, wave = threadIdx.x >> 6;
    int q = lane >> 4, c = lane & 15;
    int rowbase = blockIdx.x * 64 + wave * 16;
    int arow = rowbase + c;
    if (arow > M - 1) arow = M - 1;
    f32x4 acc[8];
#pragma unroll
    for (int i = 0; i < 8; ++i) acc[i] = (f32x4){0.f, 0.f, 0.f, 0.f};
#pragma unroll
    for (int ko = 0; ko < 4; ++ko) {
        bf16x8 af = *(const bf16x8*)(Amat + (size_t)arow * 128 + ko * 32 + q * 8);
#pragma unroll
        for (int nt = 0; nt < 8; ++nt) {
            bf16x8 bfr = *(const bf16x8*)(BT + (size_t)(nt * 16 + c) * 128 + ko * 32 + q * 8);
            acc[nt] = __builtin_amdgcn_mfma_f32_16x16x32_bf16(af, bfr, acc[nt], 0, 0, 0);
        }
    }
#pragma unroll
    for (int nt = 0; nt < 8; ++nt) {
        int col = nt * 16 + c;
        float s = colS ? colS[col] : 1.f;
        float bb = colB ? colB[col] : 0.f;
#pragma unroll
        for (int r = 0; r < 4; ++r) {
            int row = rowbase + q * 4 + r;
            if (row < M) out[(size_t)row * 128 + col] = acc[nt][r] * s + bb;
        }
    }
}

// ---------------------------------------------------------------------------
// conv2 GEMM with fused A-loader: A[row] = bf16(relu(mean3(E, pair_e[3row..])))
// ---------------------------------------------------------------------------
__global__ __launch_bounds__(256) void gemm_conv2(
    const float* __restrict__ E, const int* __restrict__ pair_e,
    const ushort* __restrict__ BT, float* __restrict__ out, int M,
    const float* __restrict__ colB) {
    int lane = threadIdx.x & 63, wave = threadIdx.x >> 6;
    int q = lane >> 4, c = lane & 15;
    int rowbase = blockIdx.x * 64 + wave * 16;
    int arow = rowbase + c;
    if (arow > M - 1) arow = M - 1;
    int e0 = pair_e[3 * arow], e1 = pair_e[3 * arow + 1], e2 = pair_e[3 * arow + 2];
    const float* p0 = E + (size_t)e0 * DD;
    const float* p1 = E + (size_t)e1 * DD;
    const float* p2 = E + (size_t)e2 * DD;
    f32x4 acc[8];
#pragma unroll
    for (int i = 0; i < 8; ++i) acc[i] = (f32x4){0.f, 0.f, 0.f, 0.f};
#pragma unroll
    for (int ko = 0; ko < 4; ++ko) {
        int offk = ko * 32 + q * 8;
        float4 u0 = *(const float4*)(p0 + offk), u1 = *(const float4*)(p0 + offk + 4);
        float4 v0 = *(const float4*)(p1 + offk), v1 = *(const float4*)(p1 + offk + 4);
        float4 w0 = *(const float4*)(p2 + offk), w1 = *(const float4*)(p2 + offk + 4);
        union { bf16x8 v; ushort u[8]; } cv;
        cv.u[0] = f2bf(fmaxf((u0.x + v0.x + w0.x) * (1.f / 3.f), 0.f));
        cv.u[1] = f2bf(fmaxf((u0.y + v0.y + w0.y) * (1.f / 3.f), 0.f));
        cv.u[2] = f2bf(fmaxf((u0.z + v0.z + w0.z) * (1.f / 3.f), 0.f));
        cv.u[3] = f2bf(fmaxf((u0.w + v0.w + w0.w) * (1.f / 3.f), 0.f));
        cv.u[4] = f2bf(fmaxf((u1.x + v1.x + w1.x) * (1.f / 3.f), 0.f));
        cv.u[5] = f2bf(fmaxf((u1.y + v1.y + w1.y) * (1.f / 3.f), 0.f));
        cv.u[6] = f2bf(fmaxf((u1.z + v1.z + w1.z) * (1.f / 3.f), 0.f));
        cv.u[7] = f2bf(fmaxf((u1.w + v1.w + w1.w) * (1.f / 3.f), 0.f));
        bf16x8 af = cv.v;
#pragma unroll
        for (int nt = 0; nt < 8; ++nt) {
            bf16x8 bfr = *(const bf16x8*)(BT + (size_t)(nt * 16 + c) * 128 + ko * 32 + q * 8);
            acc[nt] = __builtin_amdgcn_mfma_f32_16x16x32_bf16(af, bfr, acc[nt], 0, 0, 0);
        }
    }
#pragma unroll
    for (int nt = 0; nt < 8; ++nt) {
        int col = nt * 16 + c;
        float bb = colB[col];
#pragma unroll
        for (int r = 0; r < 4; ++r) {
            int row = rowbase + q * 4 + r;
            if (row < M) out[(size_t)row * 128 + col] = acc[nt][r] + bb;
        }
    }
}

// ---------------------------------------------------------------------------
// Fused k3 + gi GEMM + pred_s (mean3 inline over L2-resident E)
// ---------------------------------------------------------------------------
__global__ __launch_bounds__(256) void gemm_gi_fused(
    const int* __restrict__ in_e, const int* __restrict__ in_ed,
    const int* __restrict__ in_ep, const float* __restrict__ E,
    const int* __restrict__ pair_e,
    const float* __restrict__ cW, const float* __restrict__ cdW,
    const float* __restrict__ edW, const float* __restrict__ epW,
    const int* __restrict__ ec_map, const int* __restrict__ ecd_map,
    ushort* __restrict__ xbf,
    const ushort* __restrict__ BT, ushort* __restrict__ outg,
    const float* __restrict__ agi, const int* __restrict__ aidx,
    const int* __restrict__ ha, const int* __restrict__ ca,
    const int* __restrict__ as_, const int* __restrict__ it,
    const float* __restrict__ sd, const float* __restrict__ bs,
    float* __restrict__ outs) {
    __shared__ ushort x_s[64 * 136];
    __shared__ int sed[64], sep[64], sec[64], secd[64], sa[64];
    __shared__ int spe0[64], spe1[64], spe2[64];
    int tid = threadIdx.x;
    int rowbase_blk = blockIdx.x * 64;
    if (tid < 64) {
        int e = in_e[rowbase_blk + tid];
        sed[tid] = in_ed[rowbase_blk + tid];
        sep[tid] = in_ep[rowbase_blk + tid];
        sec[tid] = ec_map[e];
        secd[tid] = ecd_map[e];
        sa[tid] = aidx[rowbase_blk + tid];
        spe0[tid] = pair_e[3 * e];
        spe1[tid] = pair_e[3 * e + 1];
        spe2[tid] = pair_e[3 * e + 2];
    }
    __syncthreads();
#pragma unroll
    for (int i = 0; i < 8; ++i) {
        int gidx = tid + i * 256;
        int rl = gidx >> 5, dq = (gidx & 31) << 2;
        float4 m0 = *(const float4*)(E + (size_t)spe0[rl] * DD + dq);
        float4 m1 = *(const float4*)(E + (size_t)spe1[rl] * DD + dq);
        float4 m2 = *(const float4*)(E + (size_t)spe2[rl] * DD + dq);
        float4 b = *(const float4*)(cW + sec[rl] * DD + dq);
        float4 c = *(const float4*)(cdW + secd[rl] * DD + dq);
        float4 d = *(const float4*)(edW + sed[rl] * DD + dq);
        float4 g = *(const float4*)(epW + sep[rl] * DD + dq);
        float ax = (m0.x + m1.x + m2.x) * (1.f / 3.f);
        float ay = (m0.y + m1.y + m2.y) * (1.f / 3.f);
        float az = (m0.z + m1.z + m2.z) * (1.f / 3.f);
        float aw = (m0.w + m1.w + m2.w) * (1.f / 3.f);
        ushort4 o;
        o.x = f2bf(tanh_f(ax + b.x + c.x + d.x + g.x));
        o.y = f2bf(tanh_f(ay + b.y + c.y + d.y + g.y));
        o.z = f2bf(tanh_f(az + b.z + c.z + d.z + g.z));
        o.w = f2bf(tanh_f(aw + b.w + c.w + d.w + g.w));
        *(ushort4*)(x_s + rl * 136 + dq) = o;
        *(ushort4*)(xbf + (size_t)(rowbase_blk + rl) * DD + dq) = o;
    }
    __syncthreads();
    int lane = tid & 63, wave = tid >> 6;
    int q = lane >> 4, c = lane & 15;
    int rl0 = wave * 16 + c;
    f32x4 acc[24];
#pragma unroll
    for (int i = 0; i < 24; ++i) acc[i] = (f32x4){0.f, 0.f, 0.f, 0.f};
#pragma unroll
    for (int ko = 0; ko < 4; ++ko) {
        bf16x8 af = *(const bf16x8*)(x_s + rl0 * 136 + ko * 32 + q * 8);
#pragma unroll
        for (int nt = 0; nt < 24; ++nt) {
            bf16x8 bfr = *(const bf16x8*)(BT + (size_t)(nt * 16 + c) * 128 + ko * 32 + q * 8);
            acc[nt] = __builtin_amdgcn_mfma_f32_16x16x32_bf16(af, bfr, acc[nt], 0, 0, 0);
        }
    }
#pragma unroll
    for (int nt = 0; nt < 24; ++nt) {
        int col = nt * 16 + c;
#pragma unroll
        for (int r = 0; r < 4; ++r) {
            int rl = wave * 16 + q * 4 + r;
            float v = acc[nt][r] + agi[sa[rl] * 384 + col];
            outg[(size_t)(rowbase_blk + rl) * 384 + col] = f2bf(v);
        }
    }
    if (tid < 64) {
        int row = rowbase_blk + tid;
        float v = sd[ha[row]] + sd[11 + ca[row]] + sd[22 + as_[row]] + sd[30 + it[row]] + bs[0];
        outs[row] = sigm(v);
    }
}

// ---------------------------------------------------------------------------
// edge mean
// ---------------------------------------------------------------------------
__global__ __launch_bounds__(512) void edge_mean(const float* __restrict__ Y,
                                                 const int* __restrict__ list,
                                                 const int* __restrict__ start,
                                                 float* __restrict__ E) {
    __shared__ float red[4][128];
    int e = blockIdx.x;
    int d = threadIdx.x & 127, g = threadIdx.x >> 7;
    int s0 = start[e], n = start[e + 1] - s0;
    float acc = 0.f;
    for (int i = g; i < n; i += 4) acc += Y[(size_t)list[s0 + i] * DD + d];
    red[g][d] = acc;
    __syncthreads();
    if (g == 0) {
        float v = red[0][d] + red[1][d] + red[2][d] + red[3][d];
        E[e * DD + d] = v / (float)(n > 0 ? n : 1);
    }
}

// ---------------------------------------------------------------------------
// GRU scan v11: r14 structure, but the 32 per-iteration volatile pin
// statements (32 scheduling fences/iter — suspected hidden serializer: r14
// showed VALU issue is NOT binding, latency math gives ~700 cyc vs measured
// 2900) are consolidated into TWO asm statements of 16 "+a" operands each.
// Same loop-carried opacity (LICM still blocked), 16x fewer fences.
// ---------------------------------------------------------------------------
__global__ void
__attribute__((amdgpu_flat_work_group_size(768, 768)))
gru_scan(
    const ushort* __restrict__ gi, const ushort* __restrict__ xb,
    const ushort* __restrict__ UgT, const float* __restrict__ h0,
    const float* __restrict__ We, const float* __restrict__ beo_p,
    float* __restrict__ out) {
    __shared__ __align__(16) float h_s[128];
    __shared__ float p_s[128];
    __shared__ float pp[4][392];
    int b = blockIdx.x, t = threadIdx.x;
    int kq = t / 192;
    int cp = t % 192;
    const uint4* WA = (const uint4*)(UgT + (size_t)cp * 128 + kq * 32);
    const uint4* WB = (const uint4*)(UgT + (size_t)(cp + 192) * 128 + kq * 32);
    uint4 A0 = WA[0], A1 = WA[1], A2 = WA[2], A3 = WA[3];
    uint4 B0 = WB[0], B1 = WB[1], B2 = WB[2], B3 = WB[3];
    unsigned a0 = A0.x, a1 = A0.y, a2 = A0.z, a3 = A0.w;
    unsigned a4 = A1.x, a5 = A1.y, a6 = A1.z, a7 = A1.w;
    unsigned a8 = A2.x, a9 = A2.y, a10 = A2.z, a11 = A2.w;
    unsigned a12 = A3.x, a13 = A3.y, a14 = A3.z, a15 = A3.w;
    unsigned c0 = B0.x, c1 = B0.y, c2 = B0.z, c3 = B0.w;
    unsigned c4 = B1.x, c5 = B1.y, c6 = B1.z, c7 = B1.w;
    unsigned c8 = B2.x, c9 = B2.y, c10 = B2.z, c11 = B2.w;
    unsigned c12 = B3.x, c13 = B3.y, c14 = B3.z, c15 = B3.w;
    float beo = beo_p[0];
    float wev = 0.f, hreg = 0.f;
    if (t < 128) {
        wev = We[t];
        hreg = h0[b * 128 + t];
        h_s[t] = hreg;
    }
    const ushort* gip = gi + (size_t)b * SS * 384;
    const ushort* xp = xb + (size_t)b * SS * 128;
    float gz_nx = 0.f, gr_nx = 0.f, gn_nx = 0.f, xw_nx = 0.f;
    if (t < 128) {
        gz_nx = bf2f(gip[t]);
        gr_nx = bf2f(gip[128 + t]);
        gn_nx = bf2f(gip[256 + t]);
        xw_nx = bf2f(xp[t]) * wev;
    }
    float* omain = out + BSR + b * SS;
    __syncthreads();
    for (int s = 0; s < SS; ++s) {
        // AGPR residency pins: 2 fences instead of 32
        asm volatile("" : "+a"(a0), "+a"(a1), "+a"(a2), "+a"(a3), "+a"(a4), "+a"(a5),
                          "+a"(a6), "+a"(a7), "+a"(a8), "+a"(a9), "+a"(a10), "+a"(a11),
                          "+a"(a12), "+a"(a13), "+a"(a14), "+a"(a15));
        asm volatile("" : "+a"(c0), "+a"(c1), "+a"(c2), "+a"(c3), "+a"(c4), "+a"(c5),
                          "+a"(c6), "+a"(c7), "+a"(c8), "+a"(c9), "+a"(c10), "+a"(c11),
                          "+a"(c12), "+a"(c13), "+a"(c14), "+a"(c15));
        float gz = gz_nx, gr = gr_nx, gn = gn_nx, xw = xw_nx;
        if (s + 1 < SS && t < 128) {
            const ushort* g2 = gip + (size_t)(s + 1) * 384;
            gz_nx = bf2f(g2[t]);
            gr_nx = bf2f(g2[128 + t]);
            gn_nx = bf2f(g2[256 + t]);
            xw_nx = bf2f(xp[(size_t)(s + 1) * 128 + t]) * wev;
        }
        // phase A: packed matvec — per uint: 1 shift + 1 v_pk_fma_f32
        const float4* h4 = (const float4*)h_s + kq * 8;
        f32x2 accA2 = (f32x2){0.f, 0.f}, accB2 = (f32x2){0.f, 0.f};
#define FBPK(HI, U0, U1, U2, U3, V0, V1, V2, V3) { \
        float4 hv0 = h4[HI], hv1 = h4[HI + 1]; \
        f32x2 h01 = (f32x2){hv0.x, hv0.y}, h23 = (f32x2){hv0.z, hv0.w}; \
        f32x2 h45 = (f32x2){hv1.x, hv1.y}, h67 = (f32x2){hv1.z, hv1.w}; \
        accA2 = __builtin_elementwise_fma(h01, (f32x2){blo(U0), bhi(U0)}, accA2); \
        accA2 = __builtin_elementwise_fma(h23, (f32x2){blo(U1), bhi(U1)}, accA2); \
        accA2 = __builtin_elementwise_fma(h45, (f32x2){blo(U2), bhi(U2)}, accA2); \
        accA2 = __builtin_elementwise_fma(h67, (f32x2){blo(U3), bhi(U3)}, accA2); \
        accB2 = __builtin_elementwise_fma(h01, (f32x2){blo(V0), bhi(V0)}, accB2); \
        accB2 = __builtin_elementwise_fma(h23, (f32x2){blo(V1), bhi(V1)}, accB2); \
        accB2 = __builtin_elementwise_fma(h45, (f32x2){blo(V2), bhi(V2)}, accB2); \
        accB2 = __builtin_elementwise_fma(h67, (f32x2){blo(V3), bhi(V3)}, accB2); }
        FBPK(0, a0, a1, a2, a3, c0, c1, c2, c3)
        FBPK(2, a4, a5, a6, a7, c4, c5, c6, c7)
        FBPK(4, a8, a9, a10, a11, c8, c9, c10, c11)
        FBPK(6, a12, a13, a14, a15, c12, c13, c14, c15)
#undef FBPK
        pp[kq][cp] = accA2.x + accA2.y;
        pp[kq][cp + 192] = accB2.x + accB2.y;
        if (t >= 704 && s > 0) {
            int l = t - 704;
            float pv = p_s[l] + p_s[l + 64];
#pragma unroll
            for (int o = 32; o > 0; o >>= 1) pv += __shfl_xor(pv, o);
            if (l == 0) omain[s - 1] = sigm(pv + beo);
        }
        __syncthreads();
        if (t < 128) {
            float Sz = pp[0][t] + pp[1][t] + pp[2][t] + pp[3][t];
            float Sr = pp[0][128 + t] + pp[1][128 + t] + pp[2][128 + t] + pp[3][128 + t];
            float Sn = pp[0][256 + t] + pp[1][256 + t] + pp[2][256 + t] + pp[3][256 + t];
            float z = sigm(gz + Sz);
            float r = sigm(gr + Sr);
            float n = tanh_f(gn + r * Sn);
            p_s[t] = hreg * xw;
            hreg = (1.f - z) * n + z * hreg;
            h_s[t] = hreg;
        }
        __syncthreads();
    }
    if (t >= 704) {
        int l = t - 704;
        float pv = p_s[l] + p_s[l + 64];
#pragma unroll
        for (int o = 32; o > 0; o >>= 1) pv += __shfl_xor(pv, o);
        if (l == 0) omain[SS - 1] = sigm(pv + beo);
    }
}

// ---------------------------------------------------------------------------
extern "C" void kernel_launch(void* const* d_in, const int* in_sizes, int n_in,
                              void* d_out, int out_size, void* d_ws, size_t ws_size,
                              hipStream_t stream) {
    const int* in_e   = (const int*)d_in[0];
    const int* in_ed  = (const int*)d_in[1];
    const int* in_ep  = (const int*)d_in[2];
    const int* in_a   = (const int*)d_in[3];
    const int* in_as  = (const int*)d_in[4];
    const int* in_ha  = (const int*)d_in[5];
    const int* in_ca  = (const int*)d_in[6];
    const int* in_it  = (const int*)d_in[7];
    const float* deliver_h = (const float*)d_in[8];
    const int* pair_v = (const int*)d_in[9];
    const int* pair_e = (const int*)d_in[10];
    const int* ec_map = (const int*)d_in[11];
    const int* ecd_map= (const int*)d_in[12];
    const float* e_table  = (const float*)d_in[13];
    const float* c_table  = (const float*)d_in[14];
    const float* ed_table = (const float*)d_in[15];
    const float* cd_table = (const float*)d_in[16];
    const float* a_table  = (const float*)d_in[17];
    const float* it_table = (const float*)d_in[18];
    const float* ep_table = (const float*)d_in[19];
    const float* ha_table = (const float*)d_in[20];
    const float* ca_table = (const float*)d_in[21];
    const float* as_table = (const float*)d_in[22];
    const float* W1 = (const float*)d_in[23];
    const float* b1 = (const float*)d_in[24];
    const float* g1 = (const float*)d_in[25];
    const float* be1= (const float*)d_in[26];
    const float* m1 = (const float*)d_in[27];
    const float* v1 = (const float*)d_in[28];
    const float* W2 = (const float*)d_in[29];
    const float* b2 = (const float*)d_in[30];
    const float* g2 = (const float*)d_in[31];
    const float* be2= (const float*)d_in[32];
    const float* m2 = (const float*)d_in[33];
    const float* v2 = (const float*)d_in[34];
    const float* Wi = (const float*)d_in[35];
    const float* bi = (const float*)d_in[36];
    const float* Wg = (const float*)d_in[37];
    const float* Ug = (const float*)d_in[38];
    const float* bg = (const float*)d_in[39];
    const float* We = (const float*)d_in[40];
    const float* beo= (const float*)d_in[41];
    const float* Ws = (const float*)d_in[42];
    const float* bs = (const float*)d_in[43];
    float* out = (float*)d_out;
    char* ws = (char*)d_ws;

    size_t off = 0;
    auto alloc = [&](size_t bytes) { size_t o = off; off += (bytes + 255) & ~(size_t)255; return o; };
    size_t o_degcur = alloc(378 * 4);
    size_t o_start  = alloc(190 * 4);
    size_t o_list   = alloc((size_t)NPAIR * 4);
    size_t o_aff    = alloc(256 * 4);
    size_t o_W1T    = alloc(16384 * 2);
    size_t o_W2pp   = alloc(16384 * 2);
    size_t o_t2p    = alloc(128 * 4);
    size_t o_WgT    = alloc(49152 * 2);
    size_t o_UgT    = alloc(49152 * 2);
    size_t o_edW    = alloc(101 * 128 * 4);
    size_t o_epW    = alloc(101 * 128 * 4);
    size_t o_cW     = alloc(189 * 128 * 4);
    size_t o_cdW    = alloc(101 * 128 * 4);
    size_t o_agi    = alloc(2 * 384 * 4);
    size_t o_sd     = alloc(38 * 4);
    size_t o_etb    = alloc((size_t)NVD * 2);
    size_t o_E      = alloc((size_t)N_HE * DD * 4);
    size_t o_Y      = alloc((size_t)NVD * 4);
    size_t o_xbf    = alloc((size_t)BSR * DD * 2);
    size_t o_gi     = alloc((size_t)BSR * 384 * 2);

    int*    e_deg  = (int*)(ws + o_degcur);
    int*    cursor = e_deg + 189;
    int*    startp = (int*)(ws + o_start);
    int*    listp  = (int*)(ws + o_list);
    float*  aff    = (float*)(ws + o_aff);
    ushort* W1T    = (ushort*)(ws + o_W1T);
    ushort* W2ppT  = (ushort*)(ws + o_W2pp);
    float*  t2p    = (float*)(ws + o_t2p);
    ushort* WgT    = (ushort*)(ws + o_WgT);
    ushort* UgTp   = (ushort*)(ws + o_UgT);
    float*  edW    = (float*)(ws + o_edW);
    float*  epW    = (float*)(ws + o_epW);
    float*  cW     = (float*)(ws + o_cW);
    float*  cdW    = (float*)(ws + o_cdW);
    float*  agi    = (float*)(ws + o_agi);
    float*  sd     = (float*)(ws + o_sd);
    ushort* e_tb   = (ushort*)(ws + o_etb);
    float*  E      = (float*)(ws + o_E);
    float*  Y      = (float*)(ws + o_Y);
    ushort* xbf    = (ushort*)(ws + o_xbf);
    ushort* gi     = (ushort*)(ws + o_gi);

    hipMemsetAsync(ws + o_degcur, 0, 378 * 4, stream);

    P1Args pa;
    pa.pair_e = pair_e;
    pa.b1 = b1; pa.g1 = g1; pa.be1 = be1; pa.m1 = m1; pa.v1 = v1;
    pa.b2 = b2; pa.g2 = g2; pa.be2 = be2; pa.m2 = m2; pa.v2 = v2;
    pa.W1 = W1; pa.W2 = W2; pa.Wi = Wi; pa.Wg = Wg; pa.Ug = Ug; pa.e_t = e_table;
    pa.ed_t = ed_table; pa.ep_t = ep_table; pa.c_t = c_table; pa.cd_t = cd_table;
    pa.a_t = a_table; pa.bi = bi; pa.bg = bg;
    pa.ha_t = ha_table; pa.ca_t = ca_table; pa.as_t = as_table; pa.it_t = it_table; pa.Ws = Ws;
    pa.e_deg = e_deg; pa.aff = aff;
    pa.W1T = W1T; pa.W2ppT = W2ppT; pa.WgT = WgT; pa.UgT = UgTp; pa.e_tb = e_tb;
    pa.t2p = t2p; pa.edW = edW; pa.epW = epW; pa.cW = cW; pa.cdW = cdW;
    pa.agi = agi; pa.sd = sd;
    p1_kernel<<<2053, 384, 0, stream>>>(pa);

    csr_build<<<94, 384, 0, stream>>>(e_deg, pair_e, pair_v, startp, cursor, listp);

    // conv1: Y = BN1(e@W1)
    gemm_mfma8<<<(N_V + 63) / 64, 256, 0, stream>>>(e_tb, W1T, Y, N_V, aff, aff + 128);
    edge_mean<<<N_HE, 512, 0, stream>>>(Y, listp, startp, E);
    // conv2': Y = relu(mean3(E)) @ W2'' + t2'
    gemm_conv2<<<(N_V + 63) / 64, 256, 0, stream>>>(E, pair_e, W2ppT, Y, N_V, t2p);
    edge_mean<<<N_HE, 512, 0, stream>>>(Y, listp, startp, E);
    // fused k3 + gi GEMM + pred_s
    gemm_gi_fused<<<BSR / 64, 256, 0, stream>>>(in_e, in_ed, in_ep, E, pair_e, cW, cdW, edW,
                                                epW, ec_map, ecd_map, xbf, WgT, gi, agi, in_a,
                                                in_ha, in_ca, in_as, in_it, sd, bs, out);
    // GRU scan + pred_main
    gru_scan<<<BB, 768, 0, stream>>>(gi, xbf, UgTp, deliver_h, We, beo, out);
}

// Round 16
// 869.135 us; speedup vs baseline: 1.0112x; 1.0112x over previous
//
#include <hip/hip_runtime.h>

#define N_V   11965
#define N_HE  189
#define NPAIR 35895
#define BB    256
#define SS    400
#define DD    128
#define BSR   102400   // B*S rows
#define NVD   (N_V * DD)

typedef __bf16 bf16x8 __attribute__((ext_vector_type(8)));
typedef float  f32x4  __attribute__((ext_vector_type(4)));
typedef float  f32x2  __attribute__((ext_vector_type(2)));

__device__ __forceinline__ ushort f2bf(float f) {
    unsigned x = __float_as_uint(f);
    return (ushort)((x + 0x7FFFu + ((x >> 16) & 1u)) >> 16);
}
__device__ __forceinline__ float bf2f(ushort u) { return __uint_as_float(((unsigned)u) << 16); }
__device__ __forceinline__ float sigm(float x) { return 1.f / (1.f + __expf(-x)); }
__device__ __forceinline__ float tanh_f(float x) { return 2.f * sigm(2.f * x) - 1.f; }
__device__ __forceinline__ float blo(unsigned u) { return __uint_as_float(u << 16); }
__device__ __forceinline__ float bhi(unsigned u) { return __uint_as_float(u); }

// ---------------------------------------------------------------------------
// P1: fused prep — BN fold, e_deg count, transposes (W1/Wg/Ug->bf16),
// W2''=W2*diag(s2)*WiE fold (s2*W2row staged in LDS: 128 rsqrt/block not 16K),
// t2'=t2@WiE, e_table cvt, per-table folds, sdots.
// ---------------------------------------------------------------------------
struct P1Args {
    const int* pair_e;
    const float *b1, *g1, *be1, *m1, *v1;
    const float *b2, *g2, *be2, *m2, *v2;
    const float *W1, *W2, *Wi, *Wg, *Ug, *e_t;
    const float *ed_t, *ep_t, *c_t, *cd_t, *a_t, *bi, *bg;
    const float *ha_t, *ca_t, *as_t, *it_t, *Ws;
    int* e_deg;
    float* aff;
    ushort *W1T, *W2ppT, *WgT, *UgT, *e_tb;
    float *t2p, *edW, *epW, *cW, *cdW, *agi, *sd;
};

__global__ __launch_bounds__(384) void p1_kernel(P1Args A) {
    __shared__ float pref[128];
    int bid = blockIdx.x, t = threadIdx.x;
    if (bid == 0) {  // BN1 affine fold
        if (t < 128) {
            float s = A.g1[t] * rsqrtf(A.v1[t] + 1e-5f);
            A.aff[t] = s;
            A.aff[128 + t] = A.b1[t] * s + A.be1[t] - A.m1[t] * s;
        }
        return;
    }
    bid -= 1;
    if (bid < 94) {  // e_deg count
        int p = bid * 384 + t;
        if (p < NPAIR) atomicAdd(&A.e_deg[A.pair_e[p]], 1);
        return;
    }
    bid -= 94;
    if (bid < 43) {  // W1T
        int i = bid * 384 + t;
        if (i < 16384) { int k = i >> 7, n = i & 127; A.W1T[n * 128 + k] = f2bf(A.W1[i]); }
        return;
    }
    bid -= 43;
    if (bid < 128) {  // W2ppT[n][k] = bf16( sum_j (W2[k][j]*s2[j]) * Wi[j][n] )
        int k = bid;
        if (t < 128)
            pref[t] = A.W2[k * 128 + t] * (A.g2[t] * rsqrtf(A.v2[t] + 1e-5f));
        __syncthreads();
        if (t < 128) {
            float acc = 0.f;
            for (int j = 0; j < 128; ++j)
                acc += pref[j] * A.Wi[j * 128 + t];
            A.W2ppT[t * 128 + k] = f2bf(acc);
        }
        return;
    }
    bid -= 128;
    if (bid < 1) {  // t2p
        if (t < 128) {
            float acc = 0.f;
            for (int j = 0; j < 128; ++j) {
                float s2 = A.g2[j] * rsqrtf(A.v2[j] + 1e-5f);
                float t2 = A.b2[j] * s2 + A.be2[j] - A.m2[j] * s2;
                acc += t2 * A.Wi[j * 128 + t];
            }
            A.t2p[t] = acc;
        }
        return;
    }
    bid -= 1;
    if (bid < 128) {  // WgT
        int i = bid * 384 + t;
        if (i < 49152) { int k = i / 384, n = i % 384; A.WgT[n * 128 + k] = f2bf(A.Wg[i]); }
        return;
    }
    bid -= 128;
    if (bid < 128) {  // UgT
        int i = bid * 384 + t;
        if (i < 49152) { int k = i / 384, n = i % 384; A.UgT[n * 128 + k] = f2bf(A.Ug[i]); }
        return;
    }
    bid -= 128;
    if (bid < 998) {  // e_table cvt x4
        int i4 = bid * 1536 + t * 4;
        if (i4 < NVD) {
            float4 v = *(const float4*)(A.e_t + i4);
            ushort4 o;
            o.x = f2bf(v.x); o.y = f2bf(v.y); o.z = f2bf(v.z); o.w = f2bf(v.w);
            *(ushort4*)(A.e_tb + i4) = o;
        }
        return;
    }
    bid -= 998;
    if (bid < 101) {  // edW
        if (t < 128) {
            float acc = 0.f;
            for (int k = 0; k < 128; ++k)
                acc += A.ed_t[bid * 128 + k] * A.Wi[(128 + k) * 128 + t];
            A.edW[bid * 128 + t] = acc + A.bi[t];
        }
        return;
    }
    bid -= 101;
    if (bid < 101) {  // epW
        if (t < 128) {
            float acc = 0.f;
            for (int k = 0; k < 128; ++k)
                acc += A.ep_t[bid * 128 + k] * A.Wi[(256 + k) * 128 + t];
            A.epW[bid * 128 + t] = acc;
        }
        return;
    }
    bid -= 101;
    if (bid < 189) {  // cW
        if (t < 128) {
            float acc = 0.f;
            for (int k = 0; k < 128; ++k)
                acc += A.c_t[bid * 128 + k] * A.Wi[(384 + k) * 128 + t];
            A.cW[bid * 128 + t] = acc;
        }
        return;
    }
    bid -= 189;
    if (bid < 101) {  // cdW
        if (t < 128) {
            float acc = 0.f;
            for (int k = 0; k < 128; ++k)
                acc += A.cd_t[bid * 128 + k] * A.Wi[(512 + k) * 128 + t];
            A.cdW[bid * 128 + t] = acc;
        }
        return;
    }
    bid -= 101;
    if (bid < 2) {  // a_gi
        float acc = 0.f;
        for (int k = 0; k < 128; ++k)
            acc += A.a_t[bid * 128 + k] * A.Wg[(128 + k) * 384 + t];
        A.agi[bid * 384 + t] = acc + A.bg[t];
        return;
    }
    bid -= 2;
    {  // sdots (38 blocks)
        int r = bid;
        const float* tab; int woff, row;
        if (r < 11)      { tab = A.ha_t; row = r;      woff = 0;   }
        else if (r < 22) { tab = A.ca_t; row = r - 11; woff = 128; }
        else if (r < 30) { tab = A.as_t; row = r - 22; woff = 256; }
        else             { tab = A.it_t; row = r - 30; woff = 384; }
        if (t < 64) {
            float p = tab[row * 128 + t] * A.Ws[woff + t]
                    + tab[row * 128 + 64 + t] * A.Ws[woff + 64 + t];
            #pragma unroll
            for (int o = 32; o > 0; o >>= 1) p += __shfl_xor(p, o);
            if (t == 0) A.sd[r] = p;
        }
    }
}

// ---------------------------------------------------------------------------
// CSR build (fused prefix+fill)
// ---------------------------------------------------------------------------
__global__ __launch_bounds__(384) void csr_build(
    const int* __restrict__ e_deg, const int* __restrict__ pair_e,
    const int* __restrict__ pair_v, int* __restrict__ start,
    int* __restrict__ cursor, int* __restrict__ list) {
    __shared__ int sc[256];
    __shared__ int sx[256];
    int t = threadIdx.x;
    int d = 0;
    if (t < 256) { d = (t < N_HE) ? e_deg[t] : 0; sc[t] = d; }
    __syncthreads();
    for (int off = 1; off < 256; off <<= 1) {
        int v = (t < 256 && t >= off) ? sc[t - off] : 0;
        __syncthreads();
        if (t < 256) sc[t] += v;
        __syncthreads();
    }
    if (t < 256) sx[t] = sc[t] - d;
    __syncthreads();
    if (blockIdx.x == 0) {
        if (t < N_HE) start[t] = sx[t];
        if (t == 0) start[N_HE] = sc[N_HE - 1];
    }
    int p = blockIdx.x * 384 + t;
    if (p < NPAIR) {
        int e = pair_e[p];
        int pos = atomicAdd(&cursor[e], 1);
        list[sx[e] + pos] = pair_v[p];
    }
}

// ---------------------------------------------------------------------------
// conv1 GEMM (N=128): Y = BN1(e_tb @ W1)
// ---------------------------------------------------------------------------
__global__ __launch_bounds__(256) void gemm_mfma8(
    const ushort* __restrict__ Amat, const ushort* __restrict__ BT,
    float* __restrict__ out, int M,
    const float* __restrict__ colS, const float* __restrict__ colB) {
    int lane = threadIdx.x & 63, wave = threadIdx.x >> 6;
    int q = lane >> 4, c = lane & 15;
    int rowbase = blockIdx.x * 64 + wave * 16;
    int arow = rowbase + c;
    if (arow > M - 1) arow = M - 1;
    f32x4 acc[8];
#pragma unroll
    for (int i = 0; i < 8; ++i) acc[i] = (f32x4){0.f, 0.f, 0.f, 0.f};
#pragma unroll
    for (int ko = 0; ko < 4; ++ko) {
        bf16x8 af = *(const bf16x8*)(Amat + (size_t)arow * 128 + ko * 32 + q * 8);
#pragma unroll
        for (int nt = 0; nt < 8; ++nt) {
            bf16x8 bfr = *(const bf16x8*)(BT + (size_t)(nt * 16 + c) * 128 + ko * 32 + q * 8);
            acc[nt] = __builtin_amdgcn_mfma_f32_16x16x32_bf16(af, bfr, acc[nt], 0, 0, 0);
        }
    }
#pragma unroll
    for (int nt = 0; nt < 8; ++nt) {
        int col = nt * 16 + c;
        float s = colS ? colS[col] : 1.f;
        float bb = colB ? colB[col] : 0.f;
#pragma unroll
        for (int r = 0; r < 4; ++r) {
            int row = rowbase + q * 4 + r;
            if (row < M) out[(size_t)row * 128 + col] = acc[nt][r] * s + bb;
        }
    }
}

// ---------------------------------------------------------------------------
// conv2 GEMM with fused A-loader: A[row] = bf16(relu(mean3(E, pair_e[3row..])))
// ---------------------------------------------------------------------------
__global__ __launch_bounds__(256) void gemm_conv2(
    const float* __restrict__ E, const int* __restrict__ pair_e,
    const ushort* __restrict__ BT, float* __restrict__ out, int M,
    const float* __restrict__ colB) {
    int lane = threadIdx.x & 63, wave = threadIdx.x >> 6;
    int q = lane >> 4, c = lane & 15;
    int rowbase = blockIdx.x * 64 + wave * 16;
    int arow = rowbase + c;
    if (arow > M - 1) arow = M - 1;
    int e0 = pair_e[3 * arow], e1 = pair_e[3 * arow + 1], e2 = pair_e[3 * arow + 2];
    const float* p0 = E + (size_t)e0 * DD;
    const float* p1 = E + (size_t)e1 * DD;
    const float* p2 = E + (size_t)e2 * DD;
    f32x4 acc[8];
#pragma unroll
    for (int i = 0; i < 8; ++i) acc[i] = (f32x4){0.f, 0.f, 0.f, 0.f};
#pragma unroll
    for (int ko = 0; ko < 4; ++ko) {
        int offk = ko * 32 + q * 8;
        float4 u0 = *(const float4*)(p0 + offk), u1 = *(const float4*)(p0 + offk + 4);
        float4 v0 = *(const float4*)(p1 + offk), v1 = *(const float4*)(p1 + offk + 4);
        float4 w0 = *(const float4*)(p2 + offk), w1 = *(const float4*)(p2 + offk + 4);
        union { bf16x8 v; ushort u[8]; } cv;
        cv.u[0] = f2bf(fmaxf((u0.x + v0.x + w0.x) * (1.f / 3.f), 0.f));
        cv.u[1] = f2bf(fmaxf((u0.y + v0.y + w0.y) * (1.f / 3.f), 0.f));
        cv.u[2] = f2bf(fmaxf((u0.z + v0.z + w0.z) * (1.f / 3.f), 0.f));
        cv.u[3] = f2bf(fmaxf((u0.w + v0.w + w0.w) * (1.f / 3.f), 0.f));
        cv.u[4] = f2bf(fmaxf((u1.x + v1.x + w1.x) * (1.f / 3.f), 0.f));
        cv.u[5] = f2bf(fmaxf((u1.y + v1.y + w1.y) * (1.f / 3.f), 0.f));
        cv.u[6] = f2bf(fmaxf((u1.z + v1.z + w1.z) * (1.f / 3.f), 0.f));
        cv.u[7] = f2bf(fmaxf((u1.w + v1.w + w1.w) * (1.f / 3.f), 0.f));
        bf16x8 af = cv.v;
#pragma unroll
        for (int nt = 0; nt < 8; ++nt) {
            bf16x8 bfr = *(const bf16x8*)(BT + (size_t)(nt * 16 + c) * 128 + ko * 32 + q * 8);
            acc[nt] = __builtin_amdgcn_mfma_f32_16x16x32_bf16(af, bfr, acc[nt], 0, 0, 0);
        }
    }
#pragma unroll
    for (int nt = 0; nt < 8; ++nt) {
        int col = nt * 16 + c;
        float bb = colB[col];
#pragma unroll
        for (int r = 0; r < 4; ++r) {
            int row = rowbase + q * 4 + r;
            if (row < M) out[(size_t)row * 128 + col] = acc[nt][r] + bb;
        }
    }
}

// ---------------------------------------------------------------------------
// Fused k3 + gi GEMM + pred_s (mean3 inline over L2-resident E)
// ---------------------------------------------------------------------------
__global__ __launch_bounds__(256) void gemm_gi_fused(
    const int* __restrict__ in_e, const int* __restrict__ in_ed,
    const int* __restrict__ in_ep, const float* __restrict__ E,
    const int* __restrict__ pair_e,
    const float* __restrict__ cW, const float* __restrict__ cdW,
    const float* __restrict__ edW, const float* __restrict__ epW,
    const int* __restrict__ ec_map, const int* __restrict__ ecd_map,
    ushort* __restrict__ xbf,
    const ushort* __restrict__ BT, ushort* __restrict__ outg,
    const float* __restrict__ agi, const int* __restrict__ aidx,
    const int* __restrict__ ha, const int* __restrict__ ca,
    const int* __restrict__ as_, const int* __restrict__ it,
    const float* __restrict__ sd, const float* __restrict__ bs,
    float* __restrict__ outs) {
    __shared__ ushort x_s[64 * 136];
    __shared__ int sed[64], sep[64], sec[64], secd[64], sa[64];
    __shared__ int spe0[64], spe1[64], spe2[64];
    int tid = threadIdx.x;
    int rowbase_blk = blockIdx.x * 64;
    if (tid < 64) {
        int e = in_e[rowbase_blk + tid];
        sed[tid] = in_ed[rowbase_blk + tid];
        sep[tid] = in_ep[rowbase_blk + tid];
        sec[tid] = ec_map[e];
        secd[tid] = ecd_map[e];
        sa[tid] = aidx[rowbase_blk + tid];
        spe0[tid] = pair_e[3 * e];
        spe1[tid] = pair_e[3 * e + 1];
        spe2[tid] = pair_e[3 * e + 2];
    }
    __syncthreads();
#pragma unroll
    for (int i = 0; i < 8; ++i) {
        int gidx = tid + i * 256;
        int rl = gidx >> 5, dq = (gidx & 31) << 2;
        float4 m0 = *(const float4*)(E + (size_t)spe0[rl] * DD + dq);
        float4 m1 = *(const float4*)(E + (size_t)spe1[rl] * DD + dq);
        float4 m2 = *(const float4*)(E + (size_t)spe2[rl] * DD + dq);
        float4 b = *(const float4*)(cW + sec[rl] * DD + dq);
        float4 c = *(const float4*)(cdW + secd[rl] * DD + dq);
        float4 d = *(const float4*)(edW + sed[rl] * DD + dq);
        float4 g = *(const float4*)(epW + sep[rl] * DD + dq);
        float ax = (m0.x + m1.x + m2.x) * (1.f / 3.f);
        float ay = (m0.y + m1.y + m2.y) * (1.f / 3.f);
        float az = (m0.z + m1.z + m2.z) * (1.f / 3.f);
        float aw = (m0.w + m1.w + m2.w) * (1.f / 3.f);
        ushort4 o;
        o.x = f2bf(tanh_f(ax + b.x + c.x + d.x + g.x));
        o.y = f2bf(tanh_f(ay + b.y + c.y + d.y + g.y));
        o.z = f2bf(tanh_f(az + b.z + c.z + d.z + g.z));
        o.w = f2bf(tanh_f(aw + b.w + c.w + d.w + g.w));
        *(ushort4*)(x_s + rl * 136 + dq) = o;
        *(ushort4*)(xbf + (size_t)(rowbase_blk + rl) * DD + dq) = o;
    }
    __syncthreads();
    int lane = tid & 63, wave = tid >> 6;
    int q = lane >> 4, c = lane & 15;
    int rl0 = wave * 16 + c;
    f32x4 acc[24];
#pragma unroll
    for (int i = 0; i < 24; ++i) acc[i] = (f32x4){0.f, 0.f, 0.f, 0.f};
#pragma unroll
    for (int ko = 0; ko < 4; ++ko) {
        bf16x8 af = *(const bf16x8*)(x_s + rl0 * 136 + ko * 32 + q * 8);
#pragma unroll
        for (int nt = 0; nt < 24; ++nt) {
            bf16x8 bfr = *(const bf16x8*)(BT + (size_t)(nt * 16 + c) * 128 + ko * 32 + q * 8);
            acc[nt] = __builtin_amdgcn_mfma_f32_16x16x32_bf16(af, bfr, acc[nt], 0, 0, 0);
        }
    }
#pragma unroll
    for (int nt = 0; nt < 24; ++nt) {
        int col = nt * 16 + c;
#pragma unroll
        for (int r = 0; r < 4; ++r) {
            int rl = wave * 16 + q * 4 + r;
            float v = acc[nt][r] + agi[sa[rl] * 384 + col];
            outg[(size_t)(rowbase_blk + rl) * 384 + col] = f2bf(v);
        }
    }
    if (tid < 64) {
        int row = rowbase_blk + tid;
        float v = sd[ha[row]] + sd[11 + ca[row]] + sd[22 + as_[row]] + sd[30 + it[row]] + bs[0];
        outs[row] = sigm(v);
    }
}

// ---------------------------------------------------------------------------
// edge mean
// ---------------------------------------------------------------------------
__global__ __launch_bounds__(512) void edge_mean(const float* __restrict__ Y,
                                                 const int* __restrict__ list,
                                                 const int* __restrict__ start,
                                                 float* __restrict__ E) {
    __shared__ float red[4][128];
    int e = blockIdx.x;
    int d = threadIdx.x & 127, g = threadIdx.x >> 7;
    int s0 = start[e], n = start[e + 1] - s0;
    float acc = 0.f;
    for (int i = g; i < n; i += 4) acc += Y[(size_t)list[s0 + i] * DD + d];
    red[g][d] = acc;
    __syncthreads();
    if (g == 0) {
        float v = red[0][d] + red[1][d] + red[2][d] + red[3][d];
        E[e * DD + d] = v / (float)(n > 0 ? n : 1);
    }
}

// ---------------------------------------------------------------------------
// GRU scan (r14 champion, restored verbatim: 32 individual pins + pk_fma;
// r15 proved pin consolidation regresses. Structurally floored at ~480 µs:
// weight-BW, VALU-issue, and fence theories all falsified by differential
// experiments; 2-barrier scan at 1 block/CU has no filler for barrier stalls
// and the sequential recurrence forbids more blocks.)
// ---------------------------------------------------------------------------
__global__ void
__attribute__((amdgpu_flat_work_group_size(768, 768)))
gru_scan(
    const ushort* __restrict__ gi, const ushort* __restrict__ xb,
    const ushort* __restrict__ UgT, const float* __restrict__ h0,
    const float* __restrict__ We, const float* __restrict__ beo_p,
    float* __restrict__ out) {
    __shared__ __align__(16) float h_s[128];
    __shared__ float p_s[128];
    __shared__ float pp[4][392];
    int b = blockIdx.x, t = threadIdx.x;
    int kq = t / 192;
    int cp = t % 192;
    const uint4* WA = (const uint4*)(UgT + (size_t)cp * 128 + kq * 32);
    const uint4* WB = (const uint4*)(UgT + (size_t)(cp + 192) * 128 + kq * 32);
    uint4 A0 = WA[0], A1 = WA[1], A2 = WA[2], A3 = WA[3];
    uint4 B0 = WB[0], B1 = WB[1], B2 = WB[2], B3 = WB[3];
    unsigned a0 = A0.x, a1 = A0.y, a2 = A0.z, a3 = A0.w;
    unsigned a4 = A1.x, a5 = A1.y, a6 = A1.z, a7 = A1.w;
    unsigned a8 = A2.x, a9 = A2.y, a10 = A2.z, a11 = A2.w;
    unsigned a12 = A3.x, a13 = A3.y, a14 = A3.z, a15 = A3.w;
    unsigned c0 = B0.x, c1 = B0.y, c2 = B0.z, c3 = B0.w;
    unsigned c4 = B1.x, c5 = B1.y, c6 = B1.z, c7 = B1.w;
    unsigned c8 = B2.x, c9 = B2.y, c10 = B2.z, c11 = B2.w;
    unsigned c12 = B3.x, c13 = B3.y, c14 = B3.z, c15 = B3.w;
    float beo = beo_p[0];
    float wev = 0.f, hreg = 0.f;
    if (t < 128) {
        wev = We[t];
        hreg = h0[b * 128 + t];
        h_s[t] = hreg;
    }
    const ushort* gip = gi + (size_t)b * SS * 384;
    const ushort* xp = xb + (size_t)b * SS * 128;
    float gz_nx = 0.f, gr_nx = 0.f, gn_nx = 0.f, xw_nx = 0.f;
    if (t < 128) {
        gz_nx = bf2f(gip[t]);
        gr_nx = bf2f(gip[128 + t]);
        gn_nx = bf2f(gip[256 + t]);
        xw_nx = bf2f(xp[t]) * wev;
    }
    float* omain = out + BSR + b * SS;
    __syncthreads();
    for (int s = 0; s < SS; ++s) {
#define PINA(X) asm volatile("" : "+a"(X));
        PINA(a0) PINA(a1) PINA(a2) PINA(a3) PINA(a4) PINA(a5) PINA(a6) PINA(a7)
        PINA(a8) PINA(a9) PINA(a10) PINA(a11) PINA(a12) PINA(a13) PINA(a14) PINA(a15)
        PINA(c0) PINA(c1) PINA(c2) PINA(c3) PINA(c4) PINA(c5) PINA(c6) PINA(c7)
        PINA(c8) PINA(c9) PINA(c10) PINA(c11) PINA(c12) PINA(c13) PINA(c14) PINA(c15)
#undef PINA
        float gz = gz_nx, gr = gr_nx, gn = gn_nx, xw = xw_nx;
        if (s + 1 < SS && t < 128) {
            const ushort* g2 = gip + (size_t)(s + 1) * 384;
            gz_nx = bf2f(g2[t]);
            gr_nx = bf2f(g2[128 + t]);
            gn_nx = bf2f(g2[256 + t]);
            xw_nx = bf2f(xp[(size_t)(s + 1) * 128 + t]) * wev;
        }
        // phase A: packed matvec — per uint: 1 shift + 1 v_pk_fma_f32
        const float4* h4 = (const float4*)h_s + kq * 8;
        f32x2 accA2 = (f32x2){0.f, 0.f}, accB2 = (f32x2){0.f, 0.f};
#define FBPK(HI, U0, U1, U2, U3, V0, V1, V2, V3) { \
        float4 hv0 = h4[HI], hv1 = h4[HI + 1]; \
        f32x2 h01 = (f32x2){hv0.x, hv0.y}, h23 = (f32x2){hv0.z, hv0.w}; \
        f32x2 h45 = (f32x2){hv1.x, hv1.y}, h67 = (f32x2){hv1.z, hv1.w}; \
        accA2 = __builtin_elementwise_fma(h01, (f32x2){blo(U0), bhi(U0)}, accA2); \
        accA2 = __builtin_elementwise_fma(h23, (f32x2){blo(U1), bhi(U1)}, accA2); \
        accA2 = __builtin_elementwise_fma(h45, (f32x2){blo(U2), bhi(U2)}, accA2); \
        accA2 = __builtin_elementwise_fma(h67, (f32x2){blo(U3), bhi(U3)}, accA2); \
        accB2 = __builtin_elementwise_fma(h01, (f32x2){blo(V0), bhi(V0)}, accB2); \
        accB2 = __builtin_elementwise_fma(h23, (f32x2){blo(V1), bhi(V1)}, accB2); \
        accB2 = __builtin_elementwise_fma(h45, (f32x2){blo(V2), bhi(V2)}, accB2); \
        accB2 = __builtin_elementwise_fma(h67, (f32x2){blo(V3), bhi(V3)}, accB2); }
        FBPK(0, a0, a1, a2, a3, c0, c1, c2, c3)
        FBPK(2, a4, a5, a6, a7, c4, c5, c6, c7)
        FBPK(4, a8, a9, a10, a11, c8, c9, c10, c11)
        FBPK(6, a12, a13, a14, a15, c12, c13, c14, c15)
#undef FBPK
        pp[kq][cp] = accA2.x + accA2.y;
        pp[kq][cp + 192] = accB2.x + accB2.y;
        if (t >= 704 && s > 0) {
            int l = t - 704;
            float pv = p_s[l] + p_s[l + 64];
#pragma unroll
            for (int o = 32; o > 0; o >>= 1) pv += __shfl_xor(pv, o);
            if (l == 0) omain[s - 1] = sigm(pv + beo);
        }
        __syncthreads();
        if (t < 128) {
            float Sz = pp[0][t] + pp[1][t] + pp[2][t] + pp[3][t];
            float Sr = pp[0][128 + t] + pp[1][128 + t] + pp[2][128 + t] + pp[3][128 + t];
            float Sn = pp[0][256 + t] + pp[1][256 + t] + pp[2][256 + t] + pp[3][256 + t];
            float z = sigm(gz + Sz);
            float r = sigm(gr + Sr);
            float n = tanh_f(gn + r * Sn);
            p_s[t] = hreg * xw;
            hreg = (1.f - z) * n + z * hreg;
            h_s[t] = hreg;
        }
        __syncthreads();
    }
    if (t >= 704) {
        int l = t - 704;
        float pv = p_s[l] + p_s[l + 64];
#pragma unroll
        for (int o = 32; o > 0; o >>= 1) pv += __shfl_xor(pv, o);
        if (l == 0) omain[SS - 1] = sigm(pv + beo);
    }
}

// ---------------------------------------------------------------------------
extern "C" void kernel_launch(void* const* d_in, const int* in_sizes, int n_in,
                              void* d_out, int out_size, void* d_ws, size_t ws_size,
                              hipStream_t stream) {
    const int* in_e   = (const int*)d_in[0];
    const int* in_ed  = (const int*)d_in[1];
    const int* in_ep  = (const int*)d_in[2];
    const int* in_a   = (const int*)d_in[3];
    const int* in_as  = (const int*)d_in[4];
    const int* in_ha  = (const int*)d_in[5];
    const int* in_ca  = (const int*)d_in[6];
    const int* in_it  = (const int*)d_in[7];
    const float* deliver_h = (const float*)d_in[8];
    const int* pair_v = (const int*)d_in[9];
    const int* pair_e = (const int*)d_in[10];
    const int* ec_map = (const int*)d_in[11];
    const int* ecd_map= (const int*)d_in[12];
    const float* e_table  = (const float*)d_in[13];
    const float* c_table  = (const float*)d_in[14];
    const float* ed_table = (const float*)d_in[15];
    const float* cd_table = (const float*)d_in[16];
    const float* a_table  = (const float*)d_in[17];
    const float* it_table = (const float*)d_in[18];
    const float* ep_table = (const float*)d_in[19];
    const float* ha_table = (const float*)d_in[20];
    const float* ca_table = (const float*)d_in[21];
    const float* as_table = (const float*)d_in[22];
    const float* W1 = (const float*)d_in[23];
    const float* b1 = (const float*)d_in[24];
    const float* g1 = (const float*)d_in[25];
    const float* be1= (const float*)d_in[26];
    const float* m1 = (const float*)d_in[27];
    const float* v1 = (const float*)d_in[28];
    const float* W2 = (const float*)d_in[29];
    const float* b2 = (const float*)d_in[30];
    const float* g2 = (const float*)d_in[31];
    const float* be2= (const float*)d_in[32];
    const float* m2 = (const float*)d_in[33];
    const float* v2 = (const float*)d_in[34];
    const float* Wi = (const float*)d_in[35];
    const float* bi = (const float*)d_in[36];
    const float* Wg = (const float*)d_in[37];
    const float* Ug = (const float*)d_in[38];
    const float* bg = (const float*)d_in[39];
    const float* We = (const float*)d_in[40];
    const float* beo= (const float*)d_in[41];
    const float* Ws = (const float*)d_in[42];
    const float* bs = (const float*)d_in[43];
    float* out = (float*)d_out;
    char* ws = (char*)d_ws;

    size_t off = 0;
    auto alloc = [&](size_t bytes) { size_t o = off; off += (bytes + 255) & ~(size_t)255; return o; };
    size_t o_degcur = alloc(378 * 4);
    size_t o_start  = alloc(190 * 4);
    size_t o_list   = alloc((size_t)NPAIR * 4);
    size_t o_aff    = alloc(256 * 4);
    size_t o_W1T    = alloc(16384 * 2);
    size_t o_W2pp   = alloc(16384 * 2);
    size_t o_t2p    = alloc(128 * 4);
    size_t o_WgT    = alloc(49152 * 2);
    size_t o_UgT    = alloc(49152 * 2);
    size_t o_edW    = alloc(101 * 128 * 4);
    size_t o_epW    = alloc(101 * 128 * 4);
    size_t o_cW     = alloc(189 * 128 * 4);
    size_t o_cdW    = alloc(101 * 128 * 4);
    size_t o_agi    = alloc(2 * 384 * 4);
    size_t o_sd     = alloc(38 * 4);
    size_t o_etb    = alloc((size_t)NVD * 2);
    size_t o_E      = alloc((size_t)N_HE * DD * 4);
    size_t o_Y      = alloc((size_t)NVD * 4);
    size_t o_xbf    = alloc((size_t)BSR * DD * 2);
    size_t o_gi     = alloc((size_t)BSR * 384 * 2);

    int*    e_deg  = (int*)(ws + o_degcur);
    int*    cursor = e_deg + 189;
    int*    startp = (int*)(ws + o_start);
    int*    listp  = (int*)(ws + o_list);
    float*  aff    = (float*)(ws + o_aff);
    ushort* W1T    = (ushort*)(ws + o_W1T);
    ushort* W2ppT  = (ushort*)(ws + o_W2pp);
    float*  t2p    = (float*)(ws + o_t2p);
    ushort* WgT    = (ushort*)(ws + o_WgT);
    ushort* UgTp   = (ushort*)(ws + o_UgT);
    float*  edW    = (float*)(ws + o_edW);
    float*  epW    = (float*)(ws + o_epW);
    float*  cW     = (float*)(ws + o_cW);
    float*  cdW    = (float*)(ws + o_cdW);
    float*  agi    = (float*)(ws + o_agi);
    float*  sd     = (float*)(ws + o_sd);
    ushort* e_tb   = (ushort*)(ws + o_etb);
    float*  E      = (float*)(ws + o_E);
    float*  Y      = (float*)(ws + o_Y);
    ushort* xbf    = (ushort*)(ws + o_xbf);
    ushort* gi     = (ushort*)(ws + o_gi);

    hipMemsetAsync(ws + o_degcur, 0, 378 * 4, stream);

    P1Args pa;
    pa.pair_e = pair_e;
    pa.b1 = b1; pa.g1 = g1; pa.be1 = be1; pa.m1 = m1; pa.v1 = v1;
    pa.b2 = b2; pa.g2 = g2; pa.be2 = be2; pa.m2 = m2; pa.v2 = v2;
    pa.W1 = W1; pa.W2 = W2; pa.Wi = Wi; pa.Wg = Wg; pa.Ug = Ug; pa.e_t = e_table;
    pa.ed_t = ed_table; pa.ep_t = ep_table; pa.c_t = c_table; pa.cd_t = cd_table;
    pa.a_t = a_table; pa.bi = bi; pa.bg = bg;
    pa.ha_t = ha_table; pa.ca_t = ca_table; pa.as_t = as_table; pa.it_t = it_table; pa.Ws = Ws;
    pa.e_deg = e_deg; pa.aff = aff;
    pa.W1T = W1T; pa.W2ppT = W2ppT; pa.WgT = WgT; pa.UgT = UgTp; pa.e_tb = e_tb;
    pa.t2p = t2p; pa.edW = edW; pa.epW = epW; pa.cW = cW; pa.cdW = cdW;
    pa.agi = agi; pa.sd = sd;
    p1_kernel<<<2053, 384, 0, stream>>>(pa);

    csr_build<<<94, 384, 0, stream>>>(e_deg, pair_e, pair_v, startp, cursor, listp);

    // conv1: Y = BN1(e@W1)
    gemm_mfma8<<<(N_V + 63) / 64, 256, 0, stream>>>(e_tb, W1T, Y, N_V, aff, aff + 128);
    edge_mean<<<N_HE, 512, 0, stream>>>(Y, listp, startp, E);
    // conv2': Y = relu(mean3(E)) @ W2'' + t2'
    gemm_conv2<<<(N_V + 63) / 64, 256, 0, stream>>>(E, pair_e, W2ppT, Y, N_V, t2p);
    edge_mean<<<N_HE, 512, 0, stream>>>(Y, listp, startp, E);
    // fused k3 + gi GEMM + pred_s
    gemm_gi_fused<<<BSR / 64, 256, 0, stream>>>(in_e, in_ed, in_ep, E, pair_e, cW, cdW, edW,
                                                epW, ec_map, ecd_map, xbf, WgT, gi, agi, in_a,
                                                in_ha, in_ca, in_as, in_it, sd, bs, out);
    // GRU scan + pred_main
    gru_scan<<<BB, 768, 0, stream>>>(gi, xbf, UgTp, deliver_h, We, beo, out);
}